// Round 1
// baseline (275.090 us; speedup 1.0000x reference)
//
#include <hip/hip_runtime.h>
#include <hip/hip_bf16.h>

typedef _Float16 half8 __attribute__((ext_vector_type(8)));
typedef _Float16 half4v __attribute__((ext_vector_type(4)));
typedef float floatx4 __attribute__((ext_vector_type(4)));

// Problem constants: B=8, N=1024, D=512, H=8, DH=64
#define BB 8
#define NN 1024
#define DD 512
#define HH 8
#define DHH 64

// ---------------- convert x fp32 -> fp16 (vectorized) ----------------
__global__ __launch_bounds__(256) void cvt_x_kernel(const float* __restrict__ x,
                                                    _Float16* __restrict__ xh) {
    int i = blockIdx.x * 256 + threadIdx.x;   // grid sized exactly: 4096*256*4 = 4,194,304
    const float4* in = (const float4*)x;
    half4v* out = (half4v*)xh;
    float4 v = in[i];
    half4v o;
    o[0] = (_Float16)v.x; o[1] = (_Float16)v.y;
    o[2] = (_Float16)v.z; o[3] = (_Float16)v.w;
    out[i] = o;
}

// ---------------- convert + transpose W [512,512] fp32 -> Wt fp16 ----------------
// Wt[n][k] = W[k][n]  so GEMM B-fragments read contiguous 16B.
__global__ __launch_bounds__(256) void cvt_w_kernel(const float* __restrict__ Wq,
                                                    const float* __restrict__ Wk,
                                                    const float* __restrict__ Wv,
                                                    _Float16* __restrict__ Wt) {
    __shared__ __align__(16) _Float16 tb[64][72];
    int which = blockIdx.z;
    const float* W = (which == 0) ? Wq : (which == 1) ? Wk : Wv;
    _Float16* Wto = Wt + (size_t)which * DD * DD;
    int kt = blockIdx.y * 64, nt = blockIdx.x * 64;
    int tid = threadIdx.x;
    for (int i = 0; i < 16; i++) {
        int idx = tid + i * 256;
        int r = idx >> 6, c = idx & 63;
        tb[c][r] = (_Float16)W[(size_t)(kt + r) * DD + nt + c];  // coalesced read
    }
    __syncthreads();
    for (int i = 0; i < 16; i++) {
        int idx = tid + i * 256;
        int r = idx >> 6, c = idx & 63;
        Wto[(size_t)(nt + r) * DD + kt + c] = tb[r][c];          // coalesced write
    }
}

// ---------------- QKV projection: out = xh @ W + bias, fp16 out ----------------
// grid (8 ntiles, 128 mtiles, 3 which), block 256 (4 waves), 64x64 tile per block.
__global__ __launch_bounds__(256) void qkv_gemm_kernel(const _Float16* __restrict__ xh,
                                                       const _Float16* __restrict__ Wt,
                                                       const float* __restrict__ bq,
                                                       const float* __restrict__ bk,
                                                       const float* __restrict__ bv,
                                                       _Float16* __restrict__ QKV) {
    int which = blockIdx.z;
    const _Float16* Wtw = Wt + (size_t)which * DD * DD;
    const float* bias = (which == 0) ? bq : (which == 1) ? bk : bv;
    _Float16* out = QKV + (size_t)which * (BB * NN) * DD;

    int tid = threadIdx.x;
    int wave = tid >> 6, lane = tid & 63;
    int quad = lane >> 4, l16 = lane & 15;
    int m0 = blockIdx.y * 64 + wave * 16;
    int n0 = blockIdx.x * 64;

    floatx4 acc[4];
    for (int nt = 0; nt < 4; nt++) acc[nt] = (floatx4){0.f, 0.f, 0.f, 0.f};

    for (int ks = 0; ks < 16; ks++) {  // K = 512 = 16 * 32
        half8 a = *(const half8*)(xh + (size_t)(m0 + l16) * DD + ks * 32 + quad * 8);
        for (int nt = 0; nt < 4; nt++) {
            half8 b = *(const half8*)(Wtw + (size_t)(n0 + nt * 16 + l16) * DD + ks * 32 + quad * 8);
            acc[nt] = __builtin_amdgcn_mfma_f32_16x16x32_f16(a, b, acc[nt], 0, 0, 0);
        }
    }
    for (int nt = 0; nt < 4; nt++) {
        int col = n0 + nt * 16 + l16;
        float bval = bias[col];
        for (int reg = 0; reg < 4; reg++) {
            int row = m0 + quad * 4 + reg;  // C-layout: row = quad*4+reg, col = lane&15
            out[(size_t)row * DD + col] = (_Float16)(acc[nt][reg] + bval);
        }
    }
}

// ---------------- flash attention ----------------
// grid (16 qtiles, 8 heads, 8 batch), block 256 (4 waves). Br=Bc=64.
// Wave w owns Q rows [qt*64 + w*16, +16). Online softmax state per lane: 4 rows (reg).
__global__ __launch_bounds__(256) void attn_kernel(const _Float16* __restrict__ QKV,
                                                   float* __restrict__ out) {
    const _Float16* Q = QKV;
    const _Float16* K = QKV + (size_t)(BB * NN) * DD;
    const _Float16* V = QKV + (size_t)2 * (BB * NN) * DD;

    __shared__ __align__(16) _Float16 Kt[64][72];         // [key][d], pad 8 -> 2-way max
    __shared__ __align__(16) _Float16 Vt[64][72];         // [key][d]
    __shared__ __align__(16) _Float16 Pb[4][16][72];      // per-wave P strip [m][k]

    int tid = threadIdx.x;
    int wave = tid >> 6, lane = tid & 63;
    int quad = lane >> 4, l16 = lane & 15;
    int qt = blockIdx.x, h = blockIdx.y, b = blockIdx.z;

    const _Float16* Qb = Q + ((size_t)b * NN) * DD + h * DHH;
    const _Float16* Kb = K + ((size_t)b * NN) * DD + h * DHH;
    const _Float16* Vb = V + ((size_t)b * NN) * DD + h * DHH;

    // Q fragments (A-layout), held for the whole kernel
    int qrow = qt * 64 + wave * 16 + l16;
    half8 qf0 = *(const half8*)(Qb + (size_t)qrow * DD + 0 * 32 + quad * 8);
    half8 qf1 = *(const half8*)(Qb + (size_t)qrow * DD + 1 * 32 + quad * 8);

    floatx4 o[4];
    for (int nt = 0; nt < 4; nt++) o[nt] = (floatx4){0.f, 0.f, 0.f, 0.f};
    float m_i[4] = {-1e30f, -1e30f, -1e30f, -1e30f};
    float l_i[4] = {0.f, 0.f, 0.f, 0.f};

    for (int kt = 0; kt < 16; kt++) {
        __syncthreads();  // protect Kt/Vt reads of previous iteration
        for (int i = 0; i < 2; i++) {
            int r = (tid >> 3) + i * 32;
            int c = (tid & 7) * 8;
            *(half8*)&Kt[r][c] = *(const half8*)(Kb + (size_t)(kt * 64 + r) * DD + c);
            *(half8*)&Vt[r][c] = *(const half8*)(Vb + (size_t)(kt * 64 + r) * DD + c);
        }
        __syncthreads();

        // S = Q K^T : 16x64 per wave
        floatx4 s[4];
        for (int nt = 0; nt < 4; nt++) s[nt] = (floatx4){0.f, 0.f, 0.f, 0.f};
        for (int ks = 0; ks < 2; ks++) {
            half8 qf = ks ? qf1 : qf0;
            for (int nt = 0; nt < 4; nt++) {
                half8 bf = *(const half8*)&Kt[nt * 16 + l16][ks * 32 + quad * 8];
                s[nt] = __builtin_amdgcn_mfma_f32_16x16x32_f16(qf, bf, s[nt], 0, 0, 0);
            }
        }

        // online softmax: lane owns rows quad*4+reg across cols l16 + 16*nt
        float alpha[4];
        for (int reg = 0; reg < 4; reg++) {
            float mx = fmaxf(fmaxf(s[0][reg], s[1][reg]), fmaxf(s[2][reg], s[3][reg]));
            for (int off = 1; off < 16; off <<= 1) mx = fmaxf(mx, __shfl_xor(mx, off, 64));
            float mnew = fmaxf(m_i[reg], mx);
            float a = __expf(m_i[reg] - mnew);
            m_i[reg] = mnew;
            float rs = 0.f;
            for (int nt = 0; nt < 4; nt++) {
                float p = __expf(s[nt][reg] - mnew);
                s[nt][reg] = p;
                rs += p;
            }
            for (int off = 1; off < 16; off <<= 1) rs += __shfl_xor(rs, off, 64);
            l_i[reg] = l_i[reg] * a + rs;
            alpha[reg] = a;
        }

        // P: C-layout -> LDS -> A-layout (per-wave buffer; wave-internal RAW,
        // compiler inserts lgkmcnt waits)
        for (int nt = 0; nt < 4; nt++)
            for (int reg = 0; reg < 4; reg++) {
                Pb[wave][quad * 4 + reg][nt * 16 + l16] = (_Float16)s[nt][reg];
                o[nt][reg] *= alpha[reg];
            }

        // O += P V
        for (int ks = 0; ks < 2; ks++) {
            half8 pf = *(const half8*)&Pb[wave][l16][ks * 32 + quad * 8];
            for (int nt = 0; nt < 4; nt++) {
                half8 vf;
                for (int j = 0; j < 8; j++) vf[j] = Vt[ks * 32 + quad * 8 + j][nt * 16 + l16];
                o[nt] = __builtin_amdgcn_mfma_f32_16x16x32_f16(pf, vf, o[nt], 0, 0, 0);
            }
        }
    }

    float* outb = out + ((size_t)b * NN) * DD + h * DHH;
    for (int nt = 0; nt < 4; nt++)
        for (int reg = 0; reg < 4; reg++) {
            int r = qt * 64 + wave * 16 + quad * 4 + reg;
            outb[(size_t)r * DD + nt * 16 + l16] = o[nt][reg] / l_i[reg];
        }
}

extern "C" void kernel_launch(void* const* d_in, const int* in_sizes, int n_in,
                              void* d_out, int out_size, void* d_ws, size_t ws_size,
                              hipStream_t stream) {
    const float* x  = (const float*)d_in[0];
    const float* Wq = (const float*)d_in[1];
    const float* bq = (const float*)d_in[2];
    const float* Wk = (const float*)d_in[3];
    const float* bk = (const float*)d_in[4];
    const float* Wv = (const float*)d_in[5];
    const float* bv = (const float*)d_in[6];
    float* out = (float*)d_out;

    // workspace layout (halves): xh[8192*512] | Wt[3*512*512] | QKV[3*8192*512]
    _Float16* xh  = (_Float16*)d_ws;
    _Float16* Wt  = xh + (size_t)(BB * NN) * DD;
    _Float16* QKV = Wt + (size_t)3 * DD * DD;

    hipLaunchKernelGGL(cvt_x_kernel, dim3(4096), dim3(256), 0, stream, x, xh);
    hipLaunchKernelGGL(cvt_w_kernel, dim3(8, 8, 3), dim3(256), 0, stream, Wq, Wk, Wv, Wt);
    hipLaunchKernelGGL(qkv_gemm_kernel, dim3(8, 128, 3), dim3(256), 0, stream,
                       xh, Wt, bq, bk, bv, QKV);
    hipLaunchKernelGGL(attn_kernel, dim3(16, 8, 8), dim3(256), 0, stream, QKV, out);
}

// Round 2
// 171.226 us; speedup vs baseline: 1.6066x; 1.6066x over previous
//
#include <hip/hip_runtime.h>
#include <hip/hip_bf16.h>

typedef _Float16 half8 __attribute__((ext_vector_type(8)));
typedef _Float16 half4v __attribute__((ext_vector_type(4)));
typedef float floatx4 __attribute__((ext_vector_type(4)));

// Problem constants: B=8, N=1024, D=512, H=8, DH=64
#define BB 8
#define NN 1024
#define DD 512
#define HH 8
#define DHH 64

// async global->LDS, 16B per lane, dest = wave-uniform base + lane*16
__device__ __forceinline__ void gload_lds16(const _Float16* g, _Float16* l) {
    __builtin_amdgcn_global_load_lds(
        (const __attribute__((address_space(1))) void*)g,
        (__attribute__((address_space(3))) void*)l, 16, 0, 0);
}

// ---------------- convert x fp32 -> fp16 (vectorized) ----------------
__global__ __launch_bounds__(256) void cvt_x_kernel(const float* __restrict__ x,
                                                    _Float16* __restrict__ xh) {
    int i = blockIdx.x * 256 + threadIdx.x;   // 4096 blocks * 256 * 4 = 4,194,304
    const float4* in = (const float4*)x;
    half4v* out = (half4v*)xh;
    float4 v = in[i];
    half4v o;
    o[0] = (_Float16)v.x; o[1] = (_Float16)v.y;
    o[2] = (_Float16)v.z; o[3] = (_Float16)v.w;
    out[i] = o;
}

// ---------------- convert + transpose W [512,512] fp32 -> Wt fp16 ----------------
// Wt[n][k] = W[k][n]  so GEMM B-fragments read contiguous 16B.
__global__ __launch_bounds__(256) void cvt_w_kernel(const float* __restrict__ Wq,
                                                    const float* __restrict__ Wk,
                                                    const float* __restrict__ Wv,
                                                    _Float16* __restrict__ Wt) {
    __shared__ __align__(16) _Float16 tb[64][72];
    int which = blockIdx.z;
    const float* W = (which == 0) ? Wq : (which == 1) ? Wk : Wv;
    _Float16* Wto = Wt + (size_t)which * DD * DD;
    int kt = blockIdx.y * 64, nt = blockIdx.x * 64;
    int tid = threadIdx.x;
    for (int i = 0; i < 16; i++) {
        int idx = tid + i * 256;
        int r = idx >> 6, c = idx & 63;
        tb[c][r] = (_Float16)W[(size_t)(kt + r) * DD + nt + c];  // coalesced read
    }
    __syncthreads();
    for (int i = 0; i < 16; i++) {
        int idx = tid + i * 256;
        int r = idx >> 6, c = idx & 63;
        Wto[(size_t)(nt + r) * DD + kt + c] = tb[r][c];          // coalesced write
    }
}

// ---------------- QKV projection, m97-style 128x128 tile ----------------
// grid (4 ntiles, 64 mtiles, 3 which), block 256 (4 waves, 2x2), BK=32.
// Q,K written row-major [m][d]; V written TRANSPOSED as VT[b][h][dh][n].
__global__ __launch_bounds__(256) void qkv_gemm_kernel(const _Float16* __restrict__ xh,
                                                       const _Float16* __restrict__ Wt,
                                                       const float* __restrict__ bq,
                                                       const float* __restrict__ bk,
                                                       const float* __restrict__ bv,
                                                       _Float16* __restrict__ QKV) {
    __shared__ __align__(16) _Float16 As[128 * 32];  // [m][k], unpadded (global_load_lds)
    __shared__ __align__(16) _Float16 Bs[128 * 32];  // [n][k]

    int which = blockIdx.z;
    const _Float16* Wtw = Wt + (size_t)which * DD * DD;
    const float* bias = (which == 0) ? bq : (which == 1) ? bk : bv;

    int tid = threadIdx.x;
    int wave = tid >> 6, lane = tid & 63;
    int quad = lane >> 4, l16 = lane & 15;
    int wm = wave >> 1, wn = wave & 1;
    int mBase = blockIdx.y * 128, nBase = blockIdx.x * 128;

    // staging: wave covers tile rows [wave*32, wave*32+32), 2 issues of 16 rows
    int srow = wave * 32 + (lane >> 2);
    int scol = (lane & 3) * 8;
    const _Float16* ag = xh  + (size_t)(mBase + srow) * DD + scol;
    const _Float16* bg = Wtw + (size_t)(nBase + srow) * DD + scol;
    _Float16* al = As + (wave * 32) * 32;
    _Float16* bl = Bs + (wave * 32) * 32;

    floatx4 acc[4][4];
    for (int mt = 0; mt < 4; mt++)
        for (int nt = 0; nt < 4; nt++) acc[mt][nt] = (floatx4){0.f, 0.f, 0.f, 0.f};

    for (int kk = 0; kk < DD; kk += 32) {
        __syncthreads();  // previous tile fully consumed
        gload_lds16(ag + kk,            al);
        gload_lds16(ag + 16 * DD + kk,  al + 16 * 32);
        gload_lds16(bg + kk,            bl);
        gload_lds16(bg + 16 * DD + kk,  bl + 16 * 32);
        __syncthreads();  // staged (barrier drains vmcnt)

        half8 af[4], bf[4];
        for (int mt = 0; mt < 4; mt++)
            af[mt] = *(const half8*)&As[(wm * 64 + mt * 16 + l16) * 32 + quad * 8];
        for (int nt = 0; nt < 4; nt++)
            bf[nt] = *(const half8*)&Bs[(wn * 64 + nt * 16 + l16) * 32 + quad * 8];
        for (int mt = 0; mt < 4; mt++)
            for (int nt = 0; nt < 4; nt++)
                acc[mt][nt] = __builtin_amdgcn_mfma_f32_16x16x32_f16(af[mt], bf[nt], acc[mt][nt], 0, 0, 0);
    }

    if (which < 2) {
        _Float16* out = QKV + (size_t)which * (BB * NN) * DD;
        for (int nt = 0; nt < 4; nt++) {
            int col = nBase + wn * 64 + nt * 16 + l16;
            float bval = bias[col];
            for (int mt = 0; mt < 4; mt++) {
                int row0 = mBase + wm * 64 + mt * 16 + quad * 4;
                for (int reg = 0; reg < 4; reg++)
                    out[(size_t)(row0 + reg) * DD + col] = (_Float16)(acc[mt][nt][reg] + bval);
            }
        }
    } else {
        // V transposed: VT[(b*512 + col)*1024 + n], row = b*1024+n. 4 regs = consecutive n.
        _Float16* VT = QKV + (size_t)2 * (BB * NN) * DD;
        for (int nt = 0; nt < 4; nt++) {
            int col = nBase + wn * 64 + nt * 16 + l16;
            float bval = bias[col];
            for (int mt = 0; mt < 4; mt++) {
                int row0 = mBase + wm * 64 + mt * 16 + quad * 4;
                int b = row0 >> 10;
                int n = row0 & 1023;
                half4v pack;
                for (int reg = 0; reg < 4; reg++) pack[reg] = (_Float16)(acc[mt][nt][reg] + bval);
                *(half4v*)&VT[((size_t)b * 512 + col) * 1024 + n] = pack;
            }
        }
    }
}

// ---------------- flash attention ----------------
// grid (16 qtiles, 8 heads, 8 batch), block 256 (4 waves). Br=Bc=64.
// K from row-major [n][d]; V from pre-transposed VT[b][h][d][n].
__global__ __launch_bounds__(256) void attn_kernel(const _Float16* __restrict__ QKV,
                                                   float* __restrict__ out) {
    const _Float16* Q  = QKV;
    const _Float16* K  = QKV + (size_t)(BB * NN) * DD;
    const _Float16* VT = QKV + (size_t)2 * (BB * NN) * DD;

    __shared__ __align__(16) _Float16 Kt[64][72];    // [key][d], pad 8
    __shared__ __align__(16) _Float16 Vt[64][72];    // [d][key], pad 8
    __shared__ __align__(16) _Float16 Pb[4][16][72]; // per-wave P strip [m][k]

    int tid = threadIdx.x;
    int wave = tid >> 6, lane = tid & 63;
    int quad = lane >> 4, l16 = lane & 15;
    int qt = blockIdx.x, h = blockIdx.y, b = blockIdx.z;

    const _Float16* Qb  = Q + ((size_t)b * NN) * DD + h * DHH;
    const _Float16* Kb  = K + ((size_t)b * NN) * DD + h * DHH;
    const _Float16* VTb = VT + ((size_t)b * 512 + h * 64) * 1024;

    int qrow = qt * 64 + wave * 16 + l16;
    half8 qf0 = *(const half8*)(Qb + (size_t)qrow * DD + 0 * 32 + quad * 8);
    half8 qf1 = *(const half8*)(Qb + (size_t)qrow * DD + 1 * 32 + quad * 8);

    floatx4 o[4];
    for (int nt = 0; nt < 4; nt++) o[nt] = (floatx4){0.f, 0.f, 0.f, 0.f};
    float m_i[4] = {-1e30f, -1e30f, -1e30f, -1e30f};
    float l_i[4] = {0.f, 0.f, 0.f, 0.f};

    int sr = tid >> 3;            // 0..31
    int sc = (tid & 7) * 8;       // 0..56

    for (int kt = 0; kt < 16; kt++) {
        __syncthreads();  // protect Kt/Vt reads of previous iteration
        for (int i = 0; i < 2; i++) {
            int r = sr + i * 32;
            *(half8*)&Kt[r][sc] = *(const half8*)(Kb + (size_t)(kt * 64 + r) * DD + sc);
            *(half8*)&Vt[r][sc] = *(const half8*)(VTb + (size_t)r * 1024 + kt * 64 + sc);
        }
        __syncthreads();

        // S = Q K^T : 16x64 per wave
        floatx4 s[4];
        for (int nt = 0; nt < 4; nt++) s[nt] = (floatx4){0.f, 0.f, 0.f, 0.f};
        for (int ks = 0; ks < 2; ks++) {
            half8 qf = ks ? qf1 : qf0;
            for (int nt = 0; nt < 4; nt++) {
                half8 bf = *(const half8*)&Kt[nt * 16 + l16][ks * 32 + quad * 8];
                s[nt] = __builtin_amdgcn_mfma_f32_16x16x32_f16(qf, bf, s[nt], 0, 0, 0);
            }
        }

        // online softmax: lane owns rows quad*4+reg across cols l16 + 16*nt
        float alpha[4];
        for (int reg = 0; reg < 4; reg++) {
            float mx = fmaxf(fmaxf(s[0][reg], s[1][reg]), fmaxf(s[2][reg], s[3][reg]));
            for (int off = 1; off < 16; off <<= 1) mx = fmaxf(mx, __shfl_xor(mx, off, 64));
            float mnew = fmaxf(m_i[reg], mx);
            float a = __expf(m_i[reg] - mnew);
            m_i[reg] = mnew;
            float rs = 0.f;
            for (int nt = 0; nt < 4; nt++) {
                float p = __expf(s[nt][reg] - mnew);
                s[nt][reg] = p;
                rs += p;
            }
            for (int off = 1; off < 16; off <<= 1) rs += __shfl_xor(rs, off, 64);
            l_i[reg] = l_i[reg] * a + rs;
            alpha[reg] = a;
        }

        // P: C-layout -> LDS -> A-layout (per-wave buffer, wave-internal RAW)
        for (int nt = 0; nt < 4; nt++)
            for (int reg = 0; reg < 4; reg++) {
                Pb[wave][quad * 4 + reg][nt * 16 + l16] = (_Float16)s[nt][reg];
                o[nt][reg] *= alpha[reg];
            }

        // O += P V : B-fragment now contiguous from transposed Vt
        for (int ks = 0; ks < 2; ks++) {
            half8 pf = *(const half8*)&Pb[wave][l16][ks * 32 + quad * 8];
            for (int nt = 0; nt < 4; nt++) {
                half8 vf = *(const half8*)&Vt[nt * 16 + l16][ks * 32 + quad * 8];
                o[nt] = __builtin_amdgcn_mfma_f32_16x16x32_f16(pf, vf, o[nt], 0, 0, 0);
            }
        }
    }

    float* outb = out + ((size_t)b * NN) * DD + h * DHH;
    for (int nt = 0; nt < 4; nt++)
        for (int reg = 0; reg < 4; reg++) {
            int r = qt * 64 + wave * 16 + quad * 4 + reg;
            outb[(size_t)r * DD + nt * 16 + l16] = o[nt][reg] / l_i[reg];
        }
}

extern "C" void kernel_launch(void* const* d_in, const int* in_sizes, int n_in,
                              void* d_out, int out_size, void* d_ws, size_t ws_size,
                              hipStream_t stream) {
    const float* x  = (const float*)d_in[0];
    const float* Wq = (const float*)d_in[1];
    const float* bq = (const float*)d_in[2];
    const float* Wk = (const float*)d_in[3];
    const float* bk = (const float*)d_in[4];
    const float* Wv = (const float*)d_in[5];
    const float* bv = (const float*)d_in[6];
    float* out = (float*)d_out;

    // workspace (halves): xh[8192*512] | Wt[3*512*512] | QKV: Q,K row-major + VT
    _Float16* xh  = (_Float16*)d_ws;
    _Float16* Wt  = xh + (size_t)(BB * NN) * DD;
    _Float16* QKV = Wt + (size_t)3 * DD * DD;

    hipLaunchKernelGGL(cvt_x_kernel, dim3(4096), dim3(256), 0, stream, x, xh);
    hipLaunchKernelGGL(cvt_w_kernel, dim3(8, 8, 3), dim3(256), 0, stream, Wq, Wk, Wv, Wt);
    hipLaunchKernelGGL(qkv_gemm_kernel, dim3(4, 64, 3), dim3(256), 0, stream,
                       xh, Wt, bq, bk, bv, QKV);
    hipLaunchKernelGGL(attn_kernel, dim3(16, 8, 8), dim3(256), 0, stream, QKV, out);
}